// Round 9
// baseline (134.199 us; speedup 1.0000x reference)
//
#include <hip/hip_runtime.h>
#include <hip/hip_bf16.h>
#include <stdint.h>
#include <stddef.h>

#define NTOT 8192
#define BS   4096
#define DIM  1024
#define NT256 528   // 32x32 tile-grid, upper triangle: 32*33/2

// ws layout (bytes)
#define OFF_TB      0u          // bf16 total: 8192*1024*2 = 16777216
#define OFF_SQ      16777216u   // f32 [8192]
#define OFF_COLPART 16809984u   // f32 [128][1024]
#define OFF_BWP     17334272u   // f32 [8]
#define OFF_PART    17334336u   // f32 [NT256]

typedef __attribute__((ext_vector_type(8))) short bf16x8;
typedef __attribute__((ext_vector_type(4))) float f32x4;

__device__ __forceinline__ unsigned short f2bf_rne(float f) {
  unsigned u = __float_as_uint(f);
  u += 0x7fffu + ((u >> 16) & 1u);
  return (unsigned short)(u >> 16);
}

__device__ __forceinline__ float bf2f(unsigned short h) {
  return __uint_as_float((unsigned)h << 16);
}

__device__ __forceinline__ float fast_sqrt(float x) {
#if __has_builtin(__builtin_amdgcn_sqrtf)
  return __builtin_amdgcn_sqrtf(x);
#else
  float r; asm("v_sqrt_f32 %0, %1" : "=v"(r) : "v"(x)); return r;
#endif
}

__device__ __forceinline__ float fast_exp2(float x) {
#if __has_builtin(__builtin_amdgcn_exp2f)
  return __builtin_amdgcn_exp2f(x);
#else
  float r; asm("v_exp_f32 %0, %1" : "=v"(r) : "v"(x)); return r;
#endif
}

__device__ __forceinline__ void load_lds16(const void* g, void* l) {
  __builtin_amdgcn_global_load_lds((const __attribute__((address_space(1))) void*)g,
                                   (__attribute__((address_space(3))) void*)l,
                                   16, 0, 0);
}

// ---- kernel A: bf16 convert + row sums of squares (16 rows/block) ----
__global__ __launch_bounds__(256) void prep_kernel(const float* __restrict__ src,
                                                   const float* __restrict__ tgt,
                                                   unsigned short* __restrict__ tb,
                                                   float* __restrict__ sq) {
  const int t = threadIdx.x;
  const int lane = t & 63, wave = t >> 6;
  const int r0 = blockIdx.x * 16;
  __shared__ float rs[16][4];
#pragma unroll 4
  for (int r = 0; r < 16; ++r) {
    const int row = r0 + r;
    const float* base = (row < BS) ? (src + (size_t)row * DIM)
                                   : (tgt + (size_t)(row - BS) * DIM);
    float4 v = *reinterpret_cast<const float4*>(base + t * 4);
    ushort4 b;
    b.x = f2bf_rne(v.x); b.y = f2bf_rne(v.y);
    b.z = f2bf_rne(v.z); b.w = f2bf_rne(v.w);
    *reinterpret_cast<ushort4*>(tb + (size_t)row * DIM + t * 4) = b;
    float s = v.x*v.x + v.y*v.y + v.z*v.z + v.w*v.w;
#pragma unroll
    for (int off = 32; off > 0; off >>= 1) s += __shfl_down(s, off, 64);
    if (lane == 0) rs[r][wave] = s;
  }
  __syncthreads();
  if (t < 16) sq[r0 + t] = (rs[t][0] + rs[t][1]) + (rs[t][2] + rs[t][3]);
}

// ---- kernel B: column-sum partials from the cache-hot bf16 copy ----
__global__ __launch_bounds__(256) void colsum_kernel(const unsigned short* __restrict__ tb,
                                                     float* __restrict__ colpart) {
  const int g = blockIdx.x;   // 128 blocks, 64 rows each
  const int t = threadIdx.x;  // 4 cols per thread
  float a0 = 0.f, a1 = 0.f, a2 = 0.f, a3 = 0.f;
  for (int r = 0; r < 64; ++r) {
    const int row = g * 64 + r;
    ushort4 u = *reinterpret_cast<const ushort4*>(tb + (size_t)row * DIM + t * 4);
    a0 += bf2f(u.x); a1 += bf2f(u.y); a2 += bf2f(u.z); a3 += bf2f(u.w);
  }
  float4 o = {a0, a1, a2, a3};
  *reinterpret_cast<float4*>(colpart + (size_t)g * 1024 + t * 4) = o;
}

// ---- kernel C: bandwidth from analytic sum(L2) ----
__global__ __launch_bounds__(1024) void bw_kernel(const float* __restrict__ sq,
                                                  const float* __restrict__ colpart,
                                                  float* __restrict__ bwp) {
  const int t = threadIdx.x;
  double s1 = 0.0;
#pragma unroll
  for (int i = 0; i < 8; ++i) s1 += (double)sq[t + i * 1024];
  float s = 0.f;
  for (int g = 0; g < 128; ++g) s += colpart[(size_t)g * 1024 + t];
  double s2 = (double)s * (double)s;
  __shared__ double r1[1024], r2[1024];
  r1[t] = s1; r2[t] = s2;
  __syncthreads();
  for (int off = 512; off > 0; off >>= 1) {
    if (t < off) { r1[t] += r1[t + off]; r2[t] += r2[t + off]; }
    __syncthreads();
  }
  if (t == 0) {
    const double n = (double)NTOT;
    double sumL2 = 2.0 * n * r1[0] - 2.0 * r2[0];
    double bw = sumL2 / (n * n - n);
    bw = bw / 4.0;  // KERNEL_MUL^(KERNEL_NUM//2) = 2^2
    const double LOG2E = 1.4426950408889634;
    for (int k = 0; k < 5; ++k)
      bwp[k] = (float)(-LOG2E / (bw * (double)(1 << k)));  // exp2-folded
  }
}

// LDS tile [256 rows][64 k] bf16, rows of 128B = 8 16B-slots, XOR-swizzled
// (R7-verified, 0 conflicts): logical k-chunk c of row r lives at slot
// c^(r&7). gload_lds dest is linear chunk f; source carries the inverse:
// chunk f = (row f>>3, logical chunk (f&7)^((f>>3)&7)).

// stage half h (rows via chunks q=2h,2h+1; 2 gload_lds = one half-tile)
#define STG_A(dst, k0, h) do {                                                   \
    load_lds16(T + ga[2*(h)]   + (k0), (dst) + (size_t)((2*(h))*512   + wave*64)*8); \
    load_lds16(T + ga[2*(h)+1] + (k0), (dst) + (size_t)((2*(h)+1)*512 + wave*64)*8); \
  } while (0)
#define STG_B(dst, k0, h) do {                                                   \
    load_lds16(T + gb[2*(h)]   + (k0), (dst) + (size_t)((2*(h))*512   + wave*64)*8); \
    load_lds16(T + gb[2*(h)+1] + (k0), (dst) + (size_t)((2*(h)+1)*512 + wave*64)*8); \
  } while (0)

#define LDA(Abuf, MH) do {                                                       \
    _Pragma("unroll") for (int mi = 0; mi < 4; ++mi)                             \
    _Pragma("unroll") for (int kc = 0; kc < 2; ++kc)                             \
      afr[mi][kc] = *reinterpret_cast<const bf16x8*>(&(Abuf)[aoff[(MH)*4+mi][kc]]); \
  } while (0)
#define LDB(Bbuf, NH) do {                                                       \
    _Pragma("unroll") for (int ni = 0; ni < 2; ++ni)                             \
    _Pragma("unroll") for (int kc = 0; kc < 2; ++kc)                             \
      bfr[(NH)*2+ni][kc] = *reinterpret_cast<const bf16x8*>(&(Bbuf)[boff[(NH)*2+ni][kc]]); \
  } while (0)
#define MFQ(MB, NB) do {                                                         \
    __builtin_amdgcn_s_setprio(1);                                               \
    _Pragma("unroll") for (int mi = 0; mi < 4; ++mi)                             \
    _Pragma("unroll") for (int ni = 0; ni < 2; ++ni) {                           \
      acc[(MB)+mi][(NB)+ni] = __builtin_amdgcn_mfma_f32_16x16x32_bf16(           \
          afr[mi][0], bfr[(NB)+ni][0], acc[(MB)+mi][(NB)+ni], 0, 0, 0);          \
      acc[(MB)+mi][(NB)+ni] = __builtin_amdgcn_mfma_f32_16x16x32_bf16(           \
          afr[mi][1], bfr[(NB)+ni][1], acc[(MB)+mi][(NB)+ni], 0, 0, 0);          \
    }                                                                            \
    __builtin_amdgcn_s_setprio(0);                                               \
  } while (0)
#define BARR  __builtin_amdgcn_s_barrier()
#define WLG   do { asm volatile("s_waitcnt lgkmcnt(0)" ::: "memory");            \
                   __builtin_amdgcn_sched_barrier(0); } while (0)

// One K-step (BK=64) = 4 phases. Stage ledger (derived waits):
//  - C.B reads finish at ph2's closing barrier -> stage B(u+2) at ph3/ph4.
//  - C.A reads finish at ph3's closing barrier -> stage A(u+2) at ph4.
//  - vmcnt(8) at ph4: outstanding = this step's 8 stage loads; retires the
//    PREVIOUS step's 8 (= next K-step's data, issued 4 phases ago) while
//    leaving this step's 8 in flight. Never drain-0 in the loop.
#define STEP(CA, CB, u) do {                                                     \
    const int stg_ = (u) <= 13; const int k2_ = ((u) + 2) * 64;                  \
    /* ph1 */                                                                    \
    LDA(CA, 0); LDB(CB, 0);                                                      \
    BARR; WLG; MFQ(0, 0); BARR;                                                  \
    /* ph2 */                                                                    \
    LDB(CB, 1);                                                                  \
    BARR; WLG; MFQ(0, 2); BARR;                                                  \
    /* ph3 */                                                                    \
    if (stg_) STG_B(CB, k2_, 0);                                                 \
    LDA(CA, 1);                                                                  \
    BARR; WLG; MFQ(4, 2); BARR;                                                  \
    /* ph4 */                                                                    \
    if (stg_) { STG_B(CB, k2_, 1); STG_A(CA, k2_, 0); STG_A(CA, k2_, 1); }       \
    if (stg_) { asm volatile("s_waitcnt vmcnt(8)" ::: "memory"); }               \
    else      { asm volatile("s_waitcnt vmcnt(0)" ::: "memory"); }               \
    BARR; __builtin_amdgcn_sched_barrier(0); MFQ(4, 0); BARR;                    \
  } while (0)

// ---- kernel D: fused bf16 Gram GEMM + RBF epilogue, 256^2 8-phase ----
// 512 thr / 8 waves (2Mx4N), per-wave 128x64 out, BK=64, 128KB LDS dbuf.
// Triangular 32x32 tile grid (528 tiles); grid = 512 blocks: blocks 0..15
// process TWO tiles (tnos 0..31, dispatched first) to kill the 2.06-round
// tail; blocks 16..511 one tile each (XCD-chunked).
__global__ __launch_bounds__(512, 2) void mmd_gemm(const short* __restrict__ T,
                                                   const float* __restrict__ sq,
                                                   const float* __restrict__ bwp,
                                                   float* __restrict__ partials) {
  __shared__ __align__(16) short sAX[256 * 64], sBX[256 * 64];
  __shared__ __align__(16) short sAY[256 * 64], sBY[256 * 64];

  const int tid  = threadIdx.x;
  const int lane = tid & 63;
  const int wave = tid >> 6;       // 0..7
  const int wm   = wave >> 2;      // 0..1 (128-row half)
  const int wn   = wave & 3;       // 0..3 (64-col strip)
  const int r15  = lane & 15;
  const int kg   = lane >> 4;

  const int nrep = (blockIdx.x < 16) ? 2 : 1;
  for (int rep = 0; rep < nrep; ++rep) {
    int tno;
    if (blockIdx.x < 16) tno = blockIdx.x * 2 + rep;
    else { const int t2 = blockIdx.x - 16; tno = 32 + (t2 & 7) * 62 + (t2 >> 3); }

    // triangular decode over 32-grid: f(bi) = bi*(65-bi)/2
    int bi = (int)((65.0f - fast_sqrt(65.f * 65.f - 8.f * (float)tno)) * 0.5f);
    while (bi > 0 && bi * (65 - bi) / 2 > tno) --bi;
    while ((bi + 1) * (64 - bi) / 2 <= tno) ++bi;
    const int bj = bi + (tno - bi * (65 - bi) / 2);

    const size_t arow = (size_t)bi * 256;
    const size_t brow = (size_t)bj * 256;

    // staging source offsets (pre-swizzled), chunks f = q*512 + tid
    int ga[4], gb[4];
#pragma unroll
    for (int q = 0; q < 4; ++q) {
      const int f  = q * 512 + tid;
      const int sp = (f & 7) ^ ((f >> 3) & 7);
      ga[q] = (int)((arow + (f >> 3)) * DIM) + sp * 8;
      gb[q] = (int)((brow + (f >> 3)) * DIM) + sp * 8;
    }

    // ds_read offsets (shorts): row*64 + (chunk^(row&7))*8, chunk = kc*4+kg
    int aoff[8][2], boff[4][2];
#pragma unroll
    for (int m = 0; m < 8; ++m) {
      const int row = wm * 128 + m * 16 + r15;
#pragma unroll
      for (int kc = 0; kc < 2; ++kc)
        aoff[m][kc] = row * 64 + (((kc * 4 + kg) ^ (row & 7)) * 8);
    }
#pragma unroll
    for (int n = 0; n < 4; ++n) {
      const int row = wn * 64 + n * 16 + r15;
#pragma unroll
      for (int kc = 0; kc < 2; ++kc)
        boff[n][kc] = row * 64 + (((kc * 4 + kg) ^ (row & 7)) * 8);
    }

    f32x4 acc[8][4] = {};
    bf16x8 afr[4][2], bfr[4][2];

    // prologue: stage K-steps 0 (X) and 1 (Y) = 16 loads; counted vmcnt(8)
    STG_A(sAX, 0, 0);  STG_A(sAX, 0, 1);  STG_B(sBX, 0, 0);  STG_B(sBX, 0, 1);
    STG_A(sAY, 64, 0); STG_A(sAY, 64, 1); STG_B(sBY, 64, 0); STG_B(sBY, 64, 1);
    asm volatile("s_waitcnt vmcnt(8)" ::: "memory");   // step-0 landed; step-1 in flight
    BARR;

    for (int it = 0; it < 8; ++it) {
      STEP(sAX, sBX, 2 * it);
      STEP(sAY, sBY, 2 * it + 1);
    }

    // epilogue: x = l2*ni0 in exp2 domain; u = 2^(x/16);
    // sum_k exp2(x/2^k) = u + u^2 + u^4 + u^8 + u^16
    const float s16 = bwp[0] * 0.0625f;
    const float c2  = -2.f * s16;

    float ai[8][4];
#pragma unroll
    for (int m = 0; m < 8; ++m)
#pragma unroll
      for (int r = 0; r < 4; ++r)
        ai[m][r] = sq[bi * 256 + wm * 128 + m * 16 + kg * 4 + r] * s16;

    float tsum = 0.f;
#pragma unroll
    for (int n = 0; n < 4; ++n) {
      const float bjv = sq[bj * 256 + wn * 64 + n * 16 + r15] * s16;
#pragma unroll
      for (int m = 0; m < 8; ++m) {
#pragma unroll
        for (int r = 0; r < 4; ++r) {
          float x16 = fmaf(acc[m][n][r], c2, ai[m][r] + bjv);  // in [-0.9, 0]
          float u   = fast_exp2(x16);
          float u2 = u * u, u4 = u2 * u2, u8 = u4 * u4, u16 = u8 * u8;
          tsum += ((u + u2) + (u4 + u8)) + u16;
        }
      }
    }

#pragma unroll
    for (int off = 32; off > 0; off >>= 1) tsum += __shfl_down(tsum, off, 64);
    float* red = (float*)sAX;   // LDS dead after K-loop
    if (lane == 0) red[wave] = tsum;
    __syncthreads();
    if (tid == 0) {
      float sign = ((bi < 16) == (bj < 16)) ? 1.f : -1.f;
      float wgt  = (bi == bj) ? 1.f : 2.f;
      float s = 0.f;
#pragma unroll
      for (int w = 0; w < 8; ++w) s += red[w];
      partials[tno] = sign * wgt * s;
    }
    __syncthreads();   // protect red before next rep's prologue overwrites sAX
  }
}

// ---- kernel E: final reduction ----
__global__ __launch_bounds__(256) void finish_kernel(const float* __restrict__ partials,
                                                     float* __restrict__ out) {
  const int t = threadIdx.x;
  double s = 0.0;
  for (int i = t; i < NT256; i += 256) s += (double)partials[i];
  __shared__ double rd[256];
  rd[t] = s;
  __syncthreads();
  for (int off = 128; off > 0; off >>= 1) {
    if (t < off) rd[t] += rd[t + off];
    __syncthreads();
  }
  if (t == 0) out[0] = (float)(rd[0] / 16777216.0);  // / bs^2
}

extern "C" void kernel_launch(void* const* d_in, const int* in_sizes, int n_in,
                              void* d_out, int out_size, void* d_ws, size_t ws_size,
                              hipStream_t stream) {
  const float* src = (const float*)d_in[0];
  const float* tgt = (const float*)d_in[1];
  char* ws = (char*)d_ws;
  unsigned short* tb = (unsigned short*)(ws + OFF_TB);
  float* sq       = (float*)(ws + OFF_SQ);
  float* colpart  = (float*)(ws + OFF_COLPART);
  float* bwp      = (float*)(ws + OFF_BWP);
  float* partials = (float*)(ws + OFF_PART);

  prep_kernel<<<dim3(512), dim3(256), 0, stream>>>(src, tgt, tb, sq);
  colsum_kernel<<<dim3(128), dim3(256), 0, stream>>>(tb, colpart);
  bw_kernel<<<dim3(1), dim3(1024), 0, stream>>>(sq, colpart, bwp);
  mmd_gemm<<<dim3(512), dim3(512), 0, stream>>>((const short*)tb, sq, bwp, partials);
  finish_kernel<<<dim3(1), dim3(256), 0, stream>>>(partials, (float*)d_out);
}

// Round 10
// 128.067 us; speedup vs baseline: 1.0479x; 1.0479x over previous
//
#include <hip/hip_runtime.h>
#include <hip/hip_bf16.h>
#include <stdint.h>
#include <stddef.h>

#define NTOT 8192
#define BS   4096
#define DIM  1024
#define NTRI 2080   // 64*65/2 triangular tiles

// ws layout (bytes)
#define OFF_TB      0u          // bf16 total: 8192*1024*2 = 16777216
#define OFF_SQ      16777216u   // f32 [8192]
#define OFF_COLPART 16809984u   // f32 [128][1024]
#define OFF_BWP     17334272u   // f32 [8]
#define OFF_PART    17334336u   // f32 [NTRI]

typedef __attribute__((ext_vector_type(8))) short bf16x8;
typedef __attribute__((ext_vector_type(4))) float f32x4;

__device__ __forceinline__ unsigned short f2bf_rne(float f) {
  unsigned u = __float_as_uint(f);
  u += 0x7fffu + ((u >> 16) & 1u);
  return (unsigned short)(u >> 16);
}

__device__ __forceinline__ float bf2f(unsigned short h) {
  return __uint_as_float((unsigned)h << 16);
}

__device__ __forceinline__ float fast_sqrt(float x) {
#if __has_builtin(__builtin_amdgcn_sqrtf)
  return __builtin_amdgcn_sqrtf(x);
#else
  float r; asm("v_sqrt_f32 %0, %1" : "=v"(r) : "v"(x)); return r;
#endif
}

__device__ __forceinline__ float fast_exp2(float x) {
#if __has_builtin(__builtin_amdgcn_exp2f)
  return __builtin_amdgcn_exp2f(x);
#else
  float r; asm("v_exp_f32 %0, %1" : "=v"(r) : "v"(x)); return r;
#endif
}

__device__ __forceinline__ void load_lds16(const void* g, void* l) {
  __builtin_amdgcn_global_load_lds((const __attribute__((address_space(1))) void*)g,
                                   (__attribute__((address_space(3))) void*)l,
                                   16, 0, 0);
}

// ---- kernel A: bf16 convert + row sums of squares (16 rows/block) ----
__global__ __launch_bounds__(256) void prep_kernel(const float* __restrict__ src,
                                                   const float* __restrict__ tgt,
                                                   unsigned short* __restrict__ tb,
                                                   float* __restrict__ sq) {
  const int t = threadIdx.x;
  const int lane = t & 63, wave = t >> 6;
  const int r0 = blockIdx.x * 16;
  __shared__ float rs[16][4];
#pragma unroll 4
  for (int r = 0; r < 16; ++r) {
    const int row = r0 + r;
    const float* base = (row < BS) ? (src + (size_t)row * DIM)
                                   : (tgt + (size_t)(row - BS) * DIM);
    float4 v = *reinterpret_cast<const float4*>(base + t * 4);
    ushort4 b;
    b.x = f2bf_rne(v.x); b.y = f2bf_rne(v.y);
    b.z = f2bf_rne(v.z); b.w = f2bf_rne(v.w);
    *reinterpret_cast<ushort4*>(tb + (size_t)row * DIM + t * 4) = b;
    float s = v.x*v.x + v.y*v.y + v.z*v.z + v.w*v.w;
#pragma unroll
    for (int off = 32; off > 0; off >>= 1) s += __shfl_down(s, off, 64);
    if (lane == 0) rs[r][wave] = s;
  }
  __syncthreads();
  if (t < 16) sq[r0 + t] = (rs[t][0] + rs[t][1]) + (rs[t][2] + rs[t][3]);
}

// ---- kernel B: column-sum partials from the cache-hot bf16 copy ----
__global__ __launch_bounds__(256) void colsum_kernel(const unsigned short* __restrict__ tb,
                                                     float* __restrict__ colpart) {
  const int g = blockIdx.x;   // 128 blocks, 64 rows each
  const int t = threadIdx.x;  // 4 cols per thread
  float a0 = 0.f, a1 = 0.f, a2 = 0.f, a3 = 0.f;
  for (int r = 0; r < 64; ++r) {
    const int row = g * 64 + r;
    ushort4 u = *reinterpret_cast<const ushort4*>(tb + (size_t)row * DIM + t * 4);
    a0 += bf2f(u.x); a1 += bf2f(u.y); a2 += bf2f(u.z); a3 += bf2f(u.w);
  }
  float4 o = {a0, a1, a2, a3};
  *reinterpret_cast<float4*>(colpart + (size_t)g * 1024 + t * 4) = o;
}

// ---- kernel C: bandwidth from analytic sum(L2) ----
__global__ __launch_bounds__(1024) void bw_kernel(const float* __restrict__ sq,
                                                  const float* __restrict__ colpart,
                                                  float* __restrict__ bwp) {
  const int t = threadIdx.x;
  double s1 = 0.0;
#pragma unroll
  for (int i = 0; i < 8; ++i) s1 += (double)sq[t + i * 1024];
  float s = 0.f;
  for (int g = 0; g < 128; ++g) s += colpart[(size_t)g * 1024 + t];
  double s2 = (double)s * (double)s;
  __shared__ double r1[1024], r2[1024];
  r1[t] = s1; r2[t] = s2;
  __syncthreads();
  for (int off = 512; off > 0; off >>= 1) {
    if (t < off) { r1[t] += r1[t + off]; r2[t] += r2[t + off]; }
    __syncthreads();
  }
  if (t == 0) {
    const double n = (double)NTOT;
    double sumL2 = 2.0 * n * r1[0] - 2.0 * r2[0];
    double bw = sumL2 / (n * n - n);
    bw = bw / 4.0;  // KERNEL_MUL^(KERNEL_NUM//2) = 2^2
    const double LOG2E = 1.4426950408889634;
    for (int k = 0; k < 5; ++k)
      bwp[k] = (float)(-LOG2E / (bw * (double)(1 << k)));  // exp2-folded
  }
}

// LDS tile [128 rows][32 k] bf16 (64B rows = 4 16B-slots), XOR-swizzled
// (R4/R5-verified, 0 conflicts): logical chunk c of row r is at physical
// slot c^((r>>1)&3). gload_lds dest linear (chunk f -> row f>>2, slot f&3);
// global source carries the inverse: logical chunk (f&3)^((f>>3)&3).
// Stage one K=32 tile pair = 4 gload_lds per thread (A:2 + B:2).
#define STAGE(k0, ldsA, ldsB)                                                 \
  do {                                                                        \
    load_lds16(T + a0g + (k0), (ldsA) + (size_t)(wave * 64) * 8);             \
    load_lds16(T + a1g + (k0), (ldsA) + (size_t)(256 + wave * 64) * 8);       \
    load_lds16(T + b0g + (k0), (ldsB) + (size_t)(wave * 64) * 8);             \
    load_lds16(T + b1g + (k0), (ldsB) + (size_t)(256 + wave * 64) * 8);       \
  } while (0)

// one K=32 step from static buffers (swizzled ds_read): 8 b128 + 16 MFMA
#define COMPUTE32(Abuf, Bbuf)                                                 \
  do {                                                                        \
    bf16x8 a[4], b[4];                                                        \
    _Pragma("unroll")                                                         \
    for (int m = 0; m < 4; ++m)                                               \
      a[m] = *reinterpret_cast<const bf16x8*>(                                \
          &(Abuf)[(wr * 64 + m * 16 + r15) * 32 + kgx * 8]);                  \
    _Pragma("unroll")                                                         \
    for (int n = 0; n < 4; ++n)                                               \
      b[n] = *reinterpret_cast<const bf16x8*>(                                \
          &(Bbuf)[(wc * 64 + n * 16 + r15) * 32 + kgx * 8]);                  \
    _Pragma("unroll")                                                         \
    for (int m = 0; m < 4; ++m)                                               \
      _Pragma("unroll")                                                       \
      for (int n = 0; n < 4; ++n)                                             \
        acc[m][n] = __builtin_amdgcn_mfma_f32_16x16x32_bf16(a[m], b[n],       \
                                                            acc[m][n], 0, 0, 0); \
  } while (0)

#define BARR __builtin_amdgcn_s_barrier()

// ---- kernel D: fused bf16 Gram GEMM + RBF epilogue, upper-triangular tiles ----
// 128x128 tile, BK=32, 4 waves (2x2). Combines the TWO proven mechanisms:
// cross-block TLP (32KB LDS -> 4 blocks/CU, 16 waves/CU; launch_bounds(256,4)
// caps VGPR at 128) and R7's counted-vmcnt double-buffer (never drain-0 in
// the loop). Ledger (per thread, 4 loads/stage): after STAGE(next) there are
// 8 outstanding; vmcnt(4) retires exactly the CURRENT tile's 4. stage(bufX)
// is issued only after the barrier closing compute(bufX) (all reads consumed);
// compute(bufX) follows a barrier at which every wave vmcnt-confirmed bufX.
__global__ __launch_bounds__(256, 4) void mmd_gemm(const short* __restrict__ T,
                                                   const float* __restrict__ sq,
                                                   const float* __restrict__ bwp,
                                                   float* __restrict__ partials) {
  __shared__ __align__(16) short sA0[128 * 32], sA1[128 * 32];
  __shared__ __align__(16) short sB0[128 * 32], sB1[128 * 32];
  __shared__ float wred[4];

  const int tid  = threadIdx.x;
  const int lane = tid & 63;
  const int wave = tid >> 6;       // 0..3
  const int wr   = wave >> 1;      // wave row (0..1)
  const int wc   = wave & 1;       // wave col (0..1)

  // XCD-aware chunked swizzle: 8 XCDs x 260 contiguous triangular tiles
  const int tno = (blockIdx.x & 7) * 260 + (blockIdx.x >> 3);
  // triangular decode: tile tno -> (bi, bj) with bi<=bj, f(bi)=bi*(129-bi)/2
  int bi = (int)((129.0f - fast_sqrt(129.0f * 129.0f - 8.0f * (float)tno)) * 0.5f);
  while (bi > 0 && bi * (129 - bi) / 2 > tno) --bi;
  while ((bi + 1) * (129 - (bi + 1)) / 2 <= tno) ++bi;
  const int bj = bi + (tno - bi * (129 - bi) / 2);

  const size_t arow = (size_t)bi * 128;
  const size_t brow = (size_t)bj * 128;

  // staging source offsets (pre-swizzled; +k0 per tile)
  const int f0 = tid, f1 = 256 + tid;
  const int cs0 = ((f0 & 3) ^ ((f0 >> 3) & 3)) * 8;
  const int cs1 = ((f1 & 3) ^ ((f1 >> 3) & 3)) * 8;
  const int a0g = (int)((arow + (f0 >> 2)) * DIM) + cs0;
  const int a1g = (int)((arow + (f1 >> 2)) * DIM) + cs1;
  const int b0g = (int)((brow + (f0 >> 2)) * DIM) + cs0;
  const int b1g = (int)((brow + (f1 >> 2)) * DIM) + cs1;

  f32x4 acc[4][4] = {};

  const int r15 = lane & 15;
  const int kg  = lane >> 4;               // 0..3
  const int kgx = kg ^ ((r15 >> 1) & 3);   // swizzled col-chunk for ds_read

  // prologue: stage K-tile 0 into buf0 (4 loads in flight)
  STAGE(0, sA0, sB0);

  for (int t = 0; t < 16; ++t) {
    // even tile 2t in buf0; stage odd tile 2t+1 into buf1
    STAGE((2 * t + 1) * 32, sA1, sB1);
    asm volatile("s_waitcnt vmcnt(4)" ::: "memory");   // tile-2t loads landed
    BARR;
    __builtin_amdgcn_sched_barrier(0);
    COMPUTE32(sA0, sB0);
    __builtin_amdgcn_sched_barrier(0);
    BARR;                                              // buf0 reads done everywhere

    // odd tile 2t+1 in buf1; stage even tile 2t+2 into buf0
    if (t < 15) {
      STAGE((2 * t + 2) * 32, sA0, sB0);
      asm volatile("s_waitcnt vmcnt(4)" ::: "memory");
    } else {
      asm volatile("s_waitcnt vmcnt(0)" ::: "memory");
    }
    BARR;
    __builtin_amdgcn_sched_barrier(0);
    COMPUTE32(sA1, sB1);
    __builtin_amdgcn_sched_barrier(0);
    BARR;                                              // buf1 reads done everywhere
  }

  // epilogue: x = l2*ni0 in exp2 domain; u = 2^(x/16);
  // sum_k exp2(x/2^k) = u + u^2 + u^4 + u^8 + u^16  (1 trans op total)
  const float s16 = bwp[0] * 0.0625f;  // -log2e/(16*bw)
  const float c2  = -2.f * s16;
  const int hi = lane >> 4;

  float ai[4][4];
#pragma unroll
  for (int m = 0; m < 4; ++m)
#pragma unroll
    for (int r = 0; r < 4; ++r)
      ai[m][r] = sq[bi * 128 + wr * 64 + m * 16 + hi * 4 + r] * s16;

  float tsum = 0.f;
#pragma unroll
  for (int n = 0; n < 4; ++n) {
    const float bjv = sq[bj * 128 + wc * 64 + n * 16 + r15] * s16;
#pragma unroll
    for (int m = 0; m < 4; ++m) {
#pragma unroll
      for (int r = 0; r < 4; ++r) {
        float x16 = fmaf(acc[m][n][r], c2, ai[m][r] + bjv);  // in [-0.9, 0]
        float u   = fast_exp2(x16);
        float u2 = u * u, u4 = u2 * u2, u8 = u4 * u4, u16 = u8 * u8;
        tsum += ((u + u2) + (u4 + u8)) + u16;
      }
    }
  }

#pragma unroll
  for (int off = 32; off > 0; off >>= 1) tsum += __shfl_down(tsum, off, 64);
  if (lane == 0) wred[wave] = tsum;
  __syncthreads();
  if (tid == 0) {
    float sign = ((bi < 32) == (bj < 32)) ? 1.f : -1.f;
    float wgt  = (bi == bj) ? 1.f : 2.f;
    partials[tno] = sign * wgt * ((wred[0] + wred[1]) + (wred[2] + wred[3]));
  }
}

// ---- kernel E: final reduction ----
__global__ __launch_bounds__(256) void finish_kernel(const float* __restrict__ partials,
                                                     float* __restrict__ out) {
  const int t = threadIdx.x;
  double s = 0.0;
  for (int i = t; i < NTRI; i += 256) s += (double)partials[i];
  __shared__ double rd[256];
  rd[t] = s;
  __syncthreads();
  for (int off = 128; off > 0; off >>= 1) {
    if (t < off) rd[t] += rd[t + off];
    __syncthreads();
  }
  if (t == 0) out[0] = (float)(rd[0] / 16777216.0);  // / bs^2
}

extern "C" void kernel_launch(void* const* d_in, const int* in_sizes, int n_in,
                              void* d_out, int out_size, void* d_ws, size_t ws_size,
                              hipStream_t stream) {
  const float* src = (const float*)d_in[0];
  const float* tgt = (const float*)d_in[1];
  char* ws = (char*)d_ws;
  unsigned short* tb = (unsigned short*)(ws + OFF_TB);
  float* sq       = (float*)(ws + OFF_SQ);
  float* colpart  = (float*)(ws + OFF_COLPART);
  float* bwp      = (float*)(ws + OFF_BWP);
  float* partials = (float*)(ws + OFF_PART);

  prep_kernel<<<dim3(512), dim3(256), 0, stream>>>(src, tgt, tb, sq);
  colsum_kernel<<<dim3(128), dim3(256), 0, stream>>>(tb, colpart);
  bw_kernel<<<dim3(1), dim3(1024), 0, stream>>>(sq, colpart, bwp);
  mmd_gemm<<<dim3(NTRI), dim3(256), 0, stream>>>((const short*)tb, sq, bwp, partials);
  finish_kernel<<<dim3(1), dim3(256), 0, stream>>>(partials, (float*)d_out);
}

// Round 11
// 94.930 us; speedup vs baseline: 1.4137x; 1.3491x over previous
//
#include <hip/hip_runtime.h>
#include <hip/hip_bf16.h>
#include <stdint.h>
#include <stddef.h>

#define NTOT 8192
#define BS   4096
#define DIM  1024
#define NTRI 2080   // 64*65/2 triangular tiles

// ws layout (bytes)
#define OFF_TB      0u          // fp8 total: 8192*1024 = 8388608
#define OFF_SQ      8388608u    // f32 [8192]
#define OFF_COLPART 8421376u    // f32 [128][1024]
#define OFF_BWP     8945664u    // f32 [8]
#define OFF_PART    8945728u    // f32 [NTRI]

typedef __attribute__((ext_vector_type(4))) float f32x4;
typedef long long i64;

__device__ __forceinline__ float fast_sqrt(float x) {
#if __has_builtin(__builtin_amdgcn_sqrtf)
  return __builtin_amdgcn_sqrtf(x);
#else
  float r; asm("v_sqrt_f32 %0, %1" : "=v"(r) : "v"(x)); return r;
#endif
}

__device__ __forceinline__ float fast_exp2(float x) {
#if __has_builtin(__builtin_amdgcn_exp2f)
  return __builtin_amdgcn_exp2f(x);
#else
  float r; asm("v_exp_f32 %0, %1" : "=v"(r) : "v"(x)); return r;
#endif
}

__device__ __forceinline__ void load_lds16(const void* g, void* l) {
  __builtin_amdgcn_global_load_lds((const __attribute__((address_space(1))) void*)g,
                                   (__attribute__((address_space(3))) void*)l,
                                   16, 0, 0);
}

// ---- kernel A: fp8 (OCP e4m3) convert + row sums of squares (16 rows/block) ----
__global__ __launch_bounds__(256) void prep_kernel(const float* __restrict__ src,
                                                   const float* __restrict__ tgt,
                                                   unsigned char* __restrict__ tb,
                                                   float* __restrict__ sq) {
  const int t = threadIdx.x;
  const int lane = t & 63, wave = t >> 6;
  const int r0 = blockIdx.x * 16;
  __shared__ float rs[16][4];
#pragma unroll 4
  for (int r = 0; r < 16; ++r) {
    const int row = r0 + r;
    const float* base = (row < BS) ? (src + (size_t)row * DIM)
                                   : (tgt + (size_t)(row - BS) * DIM);
    float4 v = *reinterpret_cast<const float4*>(base + t * 4);
    int pk = 0;
    pk = __builtin_amdgcn_cvt_pk_fp8_f32(v.x, v.y, pk, false);  // bytes 0,1
    pk = __builtin_amdgcn_cvt_pk_fp8_f32(v.z, v.w, pk, true);   // bytes 2,3
    *reinterpret_cast<int*>(tb + (size_t)row * DIM + t * 4) = pk;
    float s = v.x*v.x + v.y*v.y + v.z*v.z + v.w*v.w;
#pragma unroll
    for (int off = 32; off > 0; off >>= 1) s += __shfl_down(s, off, 64);
    if (lane == 0) rs[r][wave] = s;
  }
  __syncthreads();
  if (t < 16) sq[r0 + t] = (rs[t][0] + rs[t][1]) + (rs[t][2] + rs[t][3]);
}

// ---- kernel B: column-sum partials from the f32 inputs (R2-proven) ----
__global__ __launch_bounds__(256) void colsum_kernel(const float* __restrict__ src,
                                                     const float* __restrict__ tgt,
                                                     float* __restrict__ colpart) {
  const int g = blockIdx.x;   // 128 blocks, 64 rows each
  const int t = threadIdx.x;  // 4 cols per thread
  float a0 = 0.f, a1 = 0.f, a2 = 0.f, a3 = 0.f;
  for (int r = 0; r < 64; ++r) {
    const int row = g * 64 + r;
    const float* base = (row < BS) ? (src + (size_t)row * DIM)
                                   : (tgt + (size_t)(row - BS) * DIM);
    float4 v = *reinterpret_cast<const float4*>(base + t * 4);
    a0 += v.x; a1 += v.y; a2 += v.z; a3 += v.w;
  }
  float4 o = {a0, a1, a2, a3};
  *reinterpret_cast<float4*>(colpart + (size_t)g * 1024 + t * 4) = o;
}

// ---- kernel C: bandwidth from analytic sum(L2) ----
__global__ __launch_bounds__(1024) void bw_kernel(const float* __restrict__ sq,
                                                  const float* __restrict__ colpart,
                                                  float* __restrict__ bwp) {
  const int t = threadIdx.x;
  double s1 = 0.0;
#pragma unroll
  for (int i = 0; i < 8; ++i) s1 += (double)sq[t + i * 1024];
  float s = 0.f;
  for (int g = 0; g < 128; ++g) s += colpart[(size_t)g * 1024 + t];
  double s2 = (double)s * (double)s;
  __shared__ double r1[1024], r2[1024];
  r1[t] = s1; r2[t] = s2;
  __syncthreads();
  for (int off = 512; off > 0; off >>= 1) {
    if (t < off) { r1[t] += r1[t + off]; r2[t] += r2[t + off]; }
    __syncthreads();
  }
  if (t == 0) {
    const double n = (double)NTOT;
    double sumL2 = 2.0 * n * r1[0] - 2.0 * r2[0];
    double bw = sumL2 / (n * n - n);
    bw = bw / 4.0;  // KERNEL_MUL^(KERNEL_NUM//2) = 2^2
    const double LOG2E = 1.4426950408889634;
    for (int k = 0; k < 5; ++k)
      bwp[k] = (float)(-LOG2E / (bw * (double)(1 << k)));  // exp2-folded
  }
}

// LDS tile [128 rows][64 k-bytes] fp8 (64B rows = 4 16B-slots), XOR-swizzled:
// logical 16B-chunk c of row r sits at physical slot c^((r>>1)&3) — same
// 64B-row geometry as the R10 bf16 layout (HW-verified 0 conflicts).
// gload_lds dest linear (chunk f -> row f>>2, slot f&3); global source
// carries the inverse: logical chunk (f&3)^((f>>3)&3).
// Read side: lane (r15,kg), k-half kk reads 8B at slot kk*2+(kg>>1) (^swz),
// half kg&1 -> wave's 64 lanes hit each bank exactly 16B/instr (balanced,
// conflict-free; derivation: banks 16*(r15&1)+4q+2h, each combo 4 lanes).
// Stage one K=64 tile pair = 4 gload_lds per thread (A:2 + B:2).
#define STAGE(k0, ldsA, ldsB)                                                 \
  do {                                                                        \
    load_lds16(T + a0g + (k0), (ldsA) + (size_t)(wave * 64) * 16);            \
    load_lds16(T + a1g + (k0), (ldsA) + (size_t)(256 + wave * 64) * 16);      \
    load_lds16(T + b0g + (k0), (ldsB) + (size_t)(wave * 64) * 16);            \
    load_lds16(T + b1g + (k0), (ldsB) + (size_t)(256 + wave * 64) * 16);      \
  } while (0)

// one K=64 step from static buffers: 2 k-halves x (8 ds_read_b64 + 16 MFMA)
#define COMPUTE64(Abuf, Bbuf)                                                 \
  do {                                                                        \
    _Pragma("unroll")                                                         \
    for (int kk = 0; kk < 2; ++kk) {                                          \
      const int okk = kk ? o1 : o0;                                           \
      i64 a[4], b[4];                                                         \
      _Pragma("unroll")                                                       \
      for (int m = 0; m < 4; ++m)                                             \
        a[m] = *reinterpret_cast<const i64*>(                                 \
            &(Abuf)[(wr * 64 + m * 16 + r15) * 64 + okk]);                    \
      _Pragma("unroll")                                                       \
      for (int n = 0; n < 4; ++n)                                             \
        b[n] = *reinterpret_cast<const i64*>(                                 \
            &(Bbuf)[(wc * 64 + n * 16 + r15) * 64 + okk]);                    \
      _Pragma("unroll")                                                       \
      for (int m = 0; m < 4; ++m)                                             \
        _Pragma("unroll")                                                     \
        for (int n = 0; n < 4; ++n)                                           \
          acc[m][n] = __builtin_amdgcn_mfma_f32_16x16x32_fp8_fp8(             \
              a[m], b[n], acc[m][n], 0, 0, 0);                                \
    }                                                                         \
  } while (0)

#define BARR __builtin_amdgcn_s_barrier()

// ---- kernel D: fused fp8 Gram GEMM + RBF epilogue, upper-triangular tiles ----
// 128x128 tile, BK=64 (fp8 bytes), 4 waves (2x2), R10's proven skeleton:
// 32KB LDS -> 4 blocks/CU TLP + counted-vmcnt dbuf (never drain-0 in loop).
// fp8 halves staged bytes (the measured binding pipe: L2->LDS ~59us at bf16)
// and halves LDS-read bytes. A,B use identical k<->byte maps -> within-K
// permutations cancel in the Gram contraction.
__global__ __launch_bounds__(256, 4) void mmd_gemm(const unsigned char* __restrict__ T,
                                                   const float* __restrict__ sq,
                                                   const float* __restrict__ bwp,
                                                   float* __restrict__ partials) {
  __shared__ __align__(16) unsigned char sA0[128 * 64], sA1[128 * 64];
  __shared__ __align__(16) unsigned char sB0[128 * 64], sB1[128 * 64];
  __shared__ float wred[4];

  const int tid  = threadIdx.x;
  const int lane = tid & 63;
  const int wave = tid >> 6;       // 0..3
  const int wr   = wave >> 1;      // wave row (0..1)
  const int wc   = wave & 1;       // wave col (0..1)

  // XCD-aware chunked swizzle: 8 XCDs x 260 contiguous triangular tiles
  const int tno = (blockIdx.x & 7) * 260 + (blockIdx.x >> 3);
  // triangular decode: tile tno -> (bi, bj) with bi<=bj, f(bi)=bi*(129-bi)/2
  int bi = (int)((129.0f - fast_sqrt(129.0f * 129.0f - 8.0f * (float)tno)) * 0.5f);
  while (bi > 0 && bi * (129 - bi) / 2 > tno) --bi;
  while ((bi + 1) * (129 - (bi + 1)) / 2 <= tno) ++bi;
  const int bj = bi + (tno - bi * (129 - bi) / 2);

  const size_t arow = (size_t)bi * 128;
  const size_t brow = (size_t)bj * 128;

  // staging source byte-offsets (pre-swizzled; +k0 bytes per tile)
  const int f0 = tid, f1 = 256 + tid;
  const int cs0 = ((f0 & 3) ^ ((f0 >> 3) & 3)) * 16;
  const int cs1 = ((f1 & 3) ^ ((f1 >> 3) & 3)) * 16;
  const int a0g = (int)((arow + (f0 >> 2)) * DIM) + cs0;
  const int a1g = (int)((arow + (f1 >> 2)) * DIM) + cs1;
  const int b0g = (int)((brow + (f0 >> 2)) * DIM) + cs0;
  const int b1g = (int)((brow + (f1 >> 2)) * DIM) + cs1;

  f32x4 acc[4][4] = {};

  const int r15 = lane & 15;
  const int kg  = lane >> 4;               // 0..3
  const int xr  = (r15 >> 1) & 3;          // row swizzle key
  // k-half kk read offset within a 64B row: slot (kk*2+(kg>>1))^xr, half kg&1
  const int o0 = (((0 * 2 + (kg >> 1)) ^ xr) * 16) + (kg & 1) * 8;
  const int o1 = (((1 * 2 + (kg >> 1)) ^ xr) * 16) + (kg & 1) * 8;

  // prologue: stage K-tile 0 into buf0 (4 loads in flight)
  STAGE(0, sA0, sB0);

  for (int t = 0; t < 8; ++t) {
    // even tile 2t in buf0; stage odd tile 2t+1 into buf1
    STAGE((2 * t + 1) * 64, sA1, sB1);
    asm volatile("s_waitcnt vmcnt(4)" ::: "memory");   // tile-2t loads landed
    BARR;
    __builtin_amdgcn_sched_barrier(0);
    COMPUTE64(sA0, sB0);
    __builtin_amdgcn_sched_barrier(0);
    BARR;                                              // buf0 reads done everywhere

    // odd tile 2t+1 in buf1; stage even tile 2t+2 into buf0
    if (t < 7) {
      STAGE((2 * t + 2) * 64, sA0, sB0);
      asm volatile("s_waitcnt vmcnt(4)" ::: "memory");
    } else {
      asm volatile("s_waitcnt vmcnt(0)" ::: "memory");
    }
    BARR;
    __builtin_amdgcn_sched_barrier(0);
    COMPUTE64(sA1, sB1);
    __builtin_amdgcn_sched_barrier(0);
    BARR;                                              // buf1 reads done everywhere
  }

  // epilogue: x = l2*ni0 in exp2 domain; u = 2^(x/16);
  // sum_k exp2(x/2^k) = u + u^2 + u^4 + u^8 + u^16  (1 trans op total)
  const float s16 = bwp[0] * 0.0625f;  // -log2e/(16*bw)
  const float c2  = -2.f * s16;
  const int hi = lane >> 4;

  float ai[4][4];
#pragma unroll
  for (int m = 0; m < 4; ++m)
#pragma unroll
    for (int r = 0; r < 4; ++r)
      ai[m][r] = sq[bi * 128 + wr * 64 + m * 16 + hi * 4 + r] * s16;

  float tsum = 0.f;
#pragma unroll
  for (int n = 0; n < 4; ++n) {
    const float bjv = sq[bj * 128 + wc * 64 + n * 16 + r15] * s16;
#pragma unroll
    for (int m = 0; m < 4; ++m) {
#pragma unroll
      for (int r = 0; r < 4; ++r) {
        float x16 = fmaf(acc[m][n][r], c2, ai[m][r] + bjv);  // in [-0.9, 0]
        float u   = fast_exp2(x16);
        float u2 = u * u, u4 = u2 * u2, u8 = u4 * u4, u16 = u8 * u8;
        tsum += ((u + u2) + (u4 + u8)) + u16;
      }
    }
  }

#pragma unroll
  for (int off = 32; off > 0; off >>= 1) tsum += __shfl_down(tsum, off, 64);
  if (lane == 0) wred[wave] = tsum;
  __syncthreads();
  if (tid == 0) {
    float sign = ((bi < 32) == (bj < 32)) ? 1.f : -1.f;
    float wgt  = (bi == bj) ? 1.f : 2.f;
    partials[tno] = sign * wgt * ((wred[0] + wred[1]) + (wred[2] + wred[3]));
  }
}

// ---- kernel E: final reduction ----
__global__ __launch_bounds__(256) void finish_kernel(const float* __restrict__ partials,
                                                     float* __restrict__ out) {
  const int t = threadIdx.x;
  double s = 0.0;
  for (int i = t; i < NTRI; i += 256) s += (double)partials[i];
  __shared__ double rd[256];
  rd[t] = s;
  __syncthreads();
  for (int off = 128; off > 0; off >>= 1) {
    if (t < off) rd[t] += rd[t + off];
    __syncthreads();
  }
  if (t == 0) out[0] = (float)(rd[0] / 16777216.0);  // / bs^2
}

extern "C" void kernel_launch(void* const* d_in, const int* in_sizes, int n_in,
                              void* d_out, int out_size, void* d_ws, size_t ws_size,
                              hipStream_t stream) {
  const float* src = (const float*)d_in[0];
  const float* tgt = (const float*)d_in[1];
  char* ws = (char*)d_ws;
  unsigned char* tb = (unsigned char*)(ws + OFF_TB);
  float* sq       = (float*)(ws + OFF_SQ);
  float* colpart  = (float*)(ws + OFF_COLPART);
  float* bwp      = (float*)(ws + OFF_BWP);
  float* partials = (float*)(ws + OFF_PART);

  prep_kernel<<<dim3(512), dim3(256), 0, stream>>>(src, tgt, tb, sq);
  colsum_kernel<<<dim3(128), dim3(256), 0, stream>>>(src, tgt, colpart);
  bw_kernel<<<dim3(1), dim3(1024), 0, stream>>>(sq, colpart, bwp);
  mmd_gemm<<<dim3(NTRI), dim3(256), 0, stream>>>(tb, sq, bwp, partials);
  finish_kernel<<<dim3(1), dim3(256), 0, stream>>>(partials, (float*)d_out);
}

// Round 13
// 85.898 us; speedup vs baseline: 1.5623x; 1.1051x over previous
//
#include <hip/hip_runtime.h>
#include <hip/hip_bf16.h>
#include <stdint.h>
#include <stddef.h>

#define NTOT 8192
#define BS   4096
#define DIM  1024
#define NTRI 2080   // 64*65/2 triangular tiles

// ws layout (bytes)
#define OFF_TB      0u          // fp8, tiled layout: 8192*1024 = 8388608
#define OFF_SQ      8388608u    // f32 [8192]
#define OFF_COLPART 8421376u    // f32 [512][1024] per-16-row col partials
#define OFF_COLP2   10518528u   // f32 [8][1024]
#define OFF_BWP     10551296u   // f32 [8]
#define OFF_PART    10551360u   // f32 [NTRI]

// tb tiled layout: element (row, k) at
//   R*16384 + kt*1024 + u*128 + r15*8 + b
// where R=row>>4, r15=row&15, kt=k>>6, u=(k>>3)&7, b=k&7.
// GEMM ds_read_b64 for row-block rb, k-half kk, lane (r15,kg) reads
//   rb*1024 + (kk*4+kg)*128 + r15*8
// -> each 16-lane group reads one consecutive 128B line: conflict-free.
// A and B share the (kg,kk)->k mapping, so the Gram contraction is exact.

typedef __attribute__((ext_vector_type(4))) float f32x4;
typedef long long i64;

__device__ __forceinline__ float fast_sqrt(float x) {
#if __has_builtin(__builtin_amdgcn_sqrtf)
  return __builtin_amdgcn_sqrtf(x);
#else
  float r; asm("v_sqrt_f32 %0, %1" : "=v"(r) : "v"(x)); return r;
#endif
}

__device__ __forceinline__ float fast_exp2(float x) {
#if __has_builtin(__builtin_amdgcn_exp2f)
  return __builtin_amdgcn_exp2f(x);
#else
  float r; asm("v_exp_f32 %0, %1" : "=v"(r) : "v"(x)); return r;
#endif
}

__device__ __forceinline__ void load_lds16(const void* g, void* l) {
  __builtin_amdgcn_global_load_lds((const __attribute__((address_space(1))) void*)g,
                                   (__attribute__((address_space(3))) void*)l,
                                   16, 0, 0);
}

// ---- kernel A: fp8 convert into tiled layout + row sq + col partials ----
__global__ __launch_bounds__(256) void prep_kernel(const float* __restrict__ src,
                                                   const float* __restrict__ tgt,
                                                   unsigned char* __restrict__ tb,
                                                   float* __restrict__ sq,
                                                   float* __restrict__ colpart) {
  const int t = threadIdx.x;
  const int lane = t & 63, wave = t >> 6;
  const int R = blockIdx.x;        // 16-row block
  const int r0 = R * 16;
  // this thread's k-columns 4t..4t+3 -> tiled position (kt, u, b4)
  const int kt = t >> 4, u = (t >> 1) & 7, b4 = (t & 1) * 4;
  unsigned char* dstbase = tb + (size_t)R * 16384 + kt * 1024 + u * 128 + b4;
  __shared__ float rs[16][4];
  float c0 = 0.f, c1 = 0.f, c2 = 0.f, c3 = 0.f;
#pragma unroll 4
  for (int r = 0; r < 16; ++r) {
    const int row = r0 + r;
    const float* base = (row < BS) ? (src + (size_t)row * DIM)
                                   : (tgt + (size_t)(row - BS) * DIM);
    float4 v = *reinterpret_cast<const float4*>(base + t * 4);
    int pk = 0;
    pk = __builtin_amdgcn_cvt_pk_fp8_f32(v.x, v.y, pk, false);  // bytes 0,1
    pk = __builtin_amdgcn_cvt_pk_fp8_f32(v.z, v.w, pk, true);   // bytes 2,3
    *reinterpret_cast<int*>(dstbase + r * 8) = pk;              // r15 = r
    c0 += v.x; c1 += v.y; c2 += v.z; c3 += v.w;
    float s = v.x*v.x + v.y*v.y + v.z*v.z + v.w*v.w;
#pragma unroll
    for (int off = 32; off > 0; off >>= 1) s += __shfl_down(s, off, 64);
    if (lane == 0) rs[r][wave] = s;
  }
  float4 cp = {c0, c1, c2, c3};
  *reinterpret_cast<float4*>(colpart + (size_t)R * 1024 + t * 4) = cp;
  __syncthreads();
  if (t < 16) sq[r0 + t] = (rs[t][0] + rs[t][1]) + (rs[t][2] + rs[t][3]);
}

// ---- kernel B: reduce 512 col-partial groups -> 8 ----
__global__ __launch_bounds__(1024) void colred_kernel(const float* __restrict__ colpart,
                                                      float* __restrict__ colp2) {
  const int b = blockIdx.x, t = threadIdx.x;   // 8 blocks x 1024 cols
  float s = 0.f;
  for (int g = b * 64; g < b * 64 + 64; ++g) s += colpart[(size_t)g * 1024 + t];
  colp2[b * 1024 + t] = s;
}

// ---- kernel C: bandwidth from analytic sum(L2) ----
__global__ __launch_bounds__(1024) void bw_kernel(const float* __restrict__ sq,
                                                  const float* __restrict__ colp2,
                                                  float* __restrict__ bwp) {
  const int t = threadIdx.x;
  double s1 = 0.0;
#pragma unroll
  for (int i = 0; i < 8; ++i) s1 += (double)sq[t + i * 1024];
  float s = 0.f;
#pragma unroll
  for (int j = 0; j < 8; ++j) s += colp2[j * 1024 + t];
  double s2 = (double)s * (double)s;
  __shared__ double r1[1024], r2[1024];
  r1[t] = s1; r2[t] = s2;
  __syncthreads();
  for (int off = 512; off > 0; off >>= 1) {
    if (t < off) { r1[t] += r1[t + off]; r2[t] += r2[t + off]; }
    __syncthreads();
  }
  if (t == 0) {
    const double n = (double)NTOT;
    double sumL2 = 2.0 * n * r1[0] - 2.0 * r2[0];
    double bw = sumL2 / (n * n - n);
    bw = bw / 4.0;  // KERNEL_MUL^(KERNEL_NUM//2) = 2^2
    const double LOG2E = 1.4426950408889634;
    for (int k = 0; k < 5; ++k)
      bwp[k] = (float)(-LOG2E / (bw * (double)(1 << k)));  // exp2-folded
  }
}

// stage one K=64 tile pair (A,B): 8KB each = 512 linear 16B chunks, 4/thread.
// Source is the tiled tb (already in LDS order) -> pure linear copy.
#define STAGE(kt1024, ldsA, ldsB)                                             \
  do {                                                                        \
    load_lds16(T + a0g + (kt1024), (ldsA) + (size_t)(wave * 64) * 16);        \
    load_lds16(T + a1g + (kt1024), (ldsA) + (size_t)(256 + wave * 64) * 16);  \
    load_lds16(T + b0g + (kt1024), (ldsB) + (size_t)(wave * 64) * 16);        \
    load_lds16(T + b1g + (kt1024), (ldsB) + (size_t)(256 + wave * 64) * 16);  \
  } while (0)

// one K=64 step: 2 k-halves x (8 ds_read_b64 + 16 MFMA); reads are
// consecutive-128B-line per 16-lane group (conflict-free). Wave's quadrant:
// A row-blocks wr*4+m, B row-blocks wc*4+n (awb/bwb byte offsets).
#define COMPUTE64(Abuf, Bbuf)                                                 \
  do {                                                                        \
    _Pragma("unroll")                                                         \
    for (int kk = 0; kk < 2; ++kk) {                                          \
      i64 a[4], b[4];                                                         \
      _Pragma("unroll")                                                       \
      for (int m = 0; m < 4; ++m)                                             \
        a[m] = *reinterpret_cast<const i64*>(                                 \
            &(Abuf)[awb + m * 1024 + kk * 512 + rbase]);                      \
      _Pragma("unroll")                                                       \
      for (int n = 0; n < 4; ++n)                                             \
        b[n] = *reinterpret_cast<const i64*>(                                 \
            &(Bbuf)[bwb + n * 1024 + kk * 512 + rbase]);                      \
      _Pragma("unroll")                                                       \
      for (int m = 0; m < 4; ++m)                                             \
        _Pragma("unroll")                                                     \
        for (int n = 0; n < 4; ++n)                                           \
          acc[m][n] = __builtin_amdgcn_mfma_f32_16x16x32_fp8_fp8(             \
              a[m], b[n], acc[m][n], 0, 0, 0);                                \
    }                                                                         \
  } while (0)

#define BARR __builtin_amdgcn_s_barrier()

// ---- kernel D: fused fp8 Gram GEMM + RBF epilogue, upper-triangular tiles ----
// 128x128 tile, BK=64 fp8, 4 waves (2x2), R11 skeleton: 32KB LDS -> 4
// blocks/CU TLP + counted-vmcnt dbuf (never drain-0 in loop). Tiled tb
// layout makes staging linear and ds_read_b64 conflict-free.
__global__ __launch_bounds__(256, 4) void mmd_gemm(const unsigned char* __restrict__ T,
                                                   const float* __restrict__ sq,
                                                   const float* __restrict__ bwp,
                                                   float* __restrict__ partials) {
  __shared__ __align__(16) unsigned char sA0[8192], sA1[8192];
  __shared__ __align__(16) unsigned char sB0[8192], sB1[8192];
  __shared__ float wred[4];

  const int tid  = threadIdx.x;
  const int lane = tid & 63;
  const int wave = tid >> 6;       // 0..3
  const int wr   = wave >> 1;      // wave row (0..1)
  const int wc   = wave & 1;       // wave col (0..1)

  // XCD-aware chunked swizzle: 8 XCDs x 260 contiguous triangular tiles
  const int tno = (blockIdx.x & 7) * 260 + (blockIdx.x >> 3);
  // triangular decode: tile tno -> (bi, bj) with bi<=bj, f(bi)=bi*(129-bi)/2
  int bi = (int)((129.0f - fast_sqrt(129.0f * 129.0f - 8.0f * (float)tno)) * 0.5f);
  while (bi > 0 && bi * (129 - bi) / 2 > tno) --bi;
  while ((bi + 1) * (129 - (bi + 1)) / 2 <= tno) ++bi;
  const int bj = bi + (tno - bi * (129 - bi) / 2);

  // row-block bases (8 x 16-row blocks per 128-row tile)
  const int aRB = bi * 8, bRB = bj * 8;

  // staging source offsets: chunk f -> row-block f>>6, 16B chunk f&63
  const int f0 = tid, f1 = 256 + tid;
  const size_t a0g = (size_t)(aRB + (f0 >> 6)) * 16384 + (f0 & 63) * 16;
  const size_t a1g = (size_t)(aRB + (f1 >> 6)) * 16384 + (f1 & 63) * 16;
  const size_t b0g = (size_t)(bRB + (f0 >> 6)) * 16384 + (f0 & 63) * 16;
  const size_t b1g = (size_t)(bRB + (f1 >> 6)) * 16384 + (f1 & 63) * 16;

  f32x4 acc[4][4] = {};

  const int r15 = lane & 15;
  const int kg  = lane >> 4;               // 0..3
  const int rbase = kg * 128 + r15 * 8;    // lane's slot within a 1KB row-block
  const int awb = wr * 4096;               // wave's A row-block byte offset
  const int bwb = wc * 4096;               // wave's B row-block byte offset

  // prologue: stage K-tile 0 into buf0 (4 loads in flight)
  STAGE(0, sA0, sB0);

  for (int t = 0; t < 8; ++t) {
    // even tile 2t in buf0; stage odd tile 2t+1 into buf1
    STAGE((2 * t + 1) * 1024, sA1, sB1);
    asm volatile("s_waitcnt vmcnt(4)" ::: "memory");   // tile-2t loads landed
    BARR;
    __builtin_amdgcn_sched_barrier(0);
    COMPUTE64(sA0, sB0);
    __builtin_amdgcn_sched_barrier(0);
    BARR;                                              // buf0 reads done everywhere

    // odd tile 2t+1 in buf1; stage even tile 2t+2 into buf0
    if (t < 7) {
      STAGE((2 * t + 2) * 1024, sA0, sB0);
      asm volatile("s_waitcnt vmcnt(4)" ::: "memory");
    } else {
      asm volatile("s_waitcnt vmcnt(0)" ::: "memory");
    }
    BARR;
    __builtin_amdgcn_sched_barrier(0);
    COMPUTE64(sA1, sB1);
    __builtin_amdgcn_sched_barrier(0);
    BARR;                                              // buf1 reads done everywhere
  }

  // epilogue: x = l2*ni0 in exp2 domain; u = 2^(x/16);
  // sum_k exp2(x/2^k) = u + u^2 + u^4 + u^8 + u^16  (1 trans op total)
  const float s16 = bwp[0] * 0.0625f;  // -log2e/(16*bw)
  const float c2  = -2.f * s16;
  const int hi = lane >> 4;

  float ai[4][4];
#pragma unroll
  for (int m = 0; m < 4; ++m)
#pragma unroll
    for (int r = 0; r < 4; ++r)
      ai[m][r] = sq[bi * 128 + wr * 64 + m * 16 + hi * 4 + r] * s16;

  float tsum = 0.f;
#pragma unroll
  for (int n = 0; n < 4; ++n) {
    const float bjv = sq[bj * 128 + wc * 64 + n * 16 + r15] * s16;
#pragma unroll
    for (int m = 0; m < 4; ++m) {
#pragma unroll
      for (int r = 0; r < 4; ++r) {
        float x16 = fmaf(acc[m][n][r], c2, ai[m][r] + bjv);  // in [-0.9, 0]
        float u   = fast_exp2(x16);
        float u2 = u * u, u4 = u2 * u2, u8 = u4 * u4, u16 = u8 * u8;
        tsum += ((u + u2) + (u4 + u8)) + u16;
      }
    }
  }

#pragma unroll
  for (int off = 32; off > 0; off >>= 1) tsum += __shfl_down(tsum, off, 64);
  if (lane == 0) wred[wave] = tsum;
  __syncthreads();
  if (tid == 0) {
    float sign = ((bi < 32) == (bj < 32)) ? 1.f : -1.f;
    float wgt  = (bi == bj) ? 1.f : 2.f;
    partials[tno] = sign * wgt * ((wred[0] + wred[1]) + (wred[2] + wred[3]));
  }
}

// ---- kernel E: final reduction ----
__global__ __launch_bounds__(256) void finish_kernel(const float* __restrict__ partials,
                                                     float* __restrict__ out) {
  const int t = threadIdx.x;
  double s = 0.0;
  for (int i = t; i < NTRI; i += 256) s += (double)partials[i];
  __shared__ double rd[256];
  rd[t] = s;
  __syncthreads();
  for (int off = 128; off > 0; off >>= 1) {
    if (t < off) rd[t] += rd[t + off];
    __syncthreads();
  }
  if (t == 0) out[0] = (float)(rd[0] / 16777216.0);  // / bs^2
}

extern "C" void kernel_launch(void* const* d_in, const int* in_sizes, int n_in,
                              void* d_out, int out_size, void* d_ws, size_t ws_size,
                              hipStream_t stream) {
  const float* src = (const float*)d_in[0];
  const float* tgt = (const float*)d_in[1];
  char* ws = (char*)d_ws;
  unsigned char* tb = (unsigned char*)(ws + OFF_TB);
  float* sq       = (float*)(ws + OFF_SQ);
  float* colpart  = (float*)(ws + OFF_COLPART);
  float* colp2    = (float*)(ws + OFF_COLP2);
  float* bwp      = (float*)(ws + OFF_BWP);
  float* partials = (float*)(ws + OFF_PART);

  prep_kernel<<<dim3(512), dim3(256), 0, stream>>>(src, tgt, tb, sq, colpart);
  colred_kernel<<<dim3(8), dim3(1024), 0, stream>>>(colpart, colp2);
  bw_kernel<<<dim3(1), dim3(1024), 0, stream>>>(sq, colp2, bwp);
  mmd_gemm<<<dim3(NTRI), dim3(256), 0, stream>>>(tb, sq, bwp, partials);
  finish_kernel<<<dim3(1), dim3(256), 0, stream>>>(partials, (float*)d_out);
}

// Round 14
// 74.598 us; speedup vs baseline: 1.7990x; 1.1515x over previous
//
#include <hip/hip_runtime.h>
#include <hip/hip_bf16.h>
#include <stdint.h>
#include <stddef.h>

#define NTOT 8192
#define BS   4096
#define DIM  1024
#define NTRI 2080   // 64*65/2 triangular tiles
#define QS   20.0f  // i8 quant scale: ±127/20 = ±6.35 sigma coverage

// ws layout (bytes)
#define OFF_TB      0u          // i8, tiled layout: 8192*1024 = 8388608
#define OFF_SQ      8388608u    // f32 [8192]
#define OFF_COLPART 8421376u    // f32 [512][1024] per-16-row col partials
#define OFF_COLP2   10518528u   // f32 [8][1024]
#define OFF_BWP     10551296u   // f32 [8]
#define OFF_PART    10551360u   // f32 [NTRI]

// tb tiled layout: element (row, k) at
//   R*16384 + kt*1024 + kq*256 + r15*16 + b
// where R=row>>4, r15=row&15, kt=k>>6, kq=(k>>4)&3, b=k&15.
// GEMM ds_read_b128 for row m (0..127), 16-k group g=(kk*2+hi32) reads
//   (m>>4)*1024 + g*256 + (m&15)*16   -- one contiguous 16B chunk;
// a 16-lane phase group reads consecutive 256B: conflict-free.
// A and B share the (lane,byte)->k mapping, so the Gram contraction is
// K-permutation-invariant (exact integer arithmetic).

typedef __attribute__((ext_vector_type(4)))  int   i32x4;
typedef __attribute__((ext_vector_type(16))) int   i32x16;

__device__ __forceinline__ float fast_sqrt(float x) {
#if __has_builtin(__builtin_amdgcn_sqrtf)
  return __builtin_amdgcn_sqrtf(x);
#else
  float r; asm("v_sqrt_f32 %0, %1" : "=v"(r) : "v"(x)); return r;
#endif
}

__device__ __forceinline__ float fast_exp2(float x) {
#if __has_builtin(__builtin_amdgcn_exp2f)
  return __builtin_amdgcn_exp2f(x);
#else
  float r; asm("v_exp_f32 %0, %1" : "=v"(r) : "v"(x)); return r;
#endif
}

__device__ __forceinline__ void load_lds16(const void* g, void* l) {
  __builtin_amdgcn_global_load_lds((const __attribute__((address_space(1))) void*)g,
                                   (__attribute__((address_space(3))) void*)l,
                                   16, 0, 0);
}

__device__ __forceinline__ int quant4(float4 v) {
  int q0 = __float2int_rn(fminf(fmaxf(v.x * QS, -127.f), 127.f));
  int q1 = __float2int_rn(fminf(fmaxf(v.y * QS, -127.f), 127.f));
  int q2 = __float2int_rn(fminf(fmaxf(v.z * QS, -127.f), 127.f));
  int q3 = __float2int_rn(fminf(fmaxf(v.w * QS, -127.f), 127.f));
  return (q0 & 255) | ((q1 & 255) << 8) | ((q2 & 255) << 16) | ((q3 & 255) << 24);
}

// ---- kernel A: i8 quantize into tiled layout + row sq + col partials ----
__global__ __launch_bounds__(256) void prep_kernel(const float* __restrict__ src,
                                                   const float* __restrict__ tgt,
                                                   unsigned char* __restrict__ tb,
                                                   float* __restrict__ sq,
                                                   float* __restrict__ colpart) {
  const int t = threadIdx.x;
  const int lane = t & 63, wave = t >> 6;
  const int R = blockIdx.x;        // 16-row block
  const int r0 = R * 16;
  // this thread's k-columns 4t..4t+3 -> tiled position (kt, kq, b0)
  const int kt = t >> 4, kq = (t >> 2) & 3, b0 = (t & 3) * 4;
  unsigned char* dstbase = tb + (size_t)R * 16384 + kt * 1024 + kq * 256 + b0;
  __shared__ float rs[16][4];
  float c0 = 0.f, c1 = 0.f, c2 = 0.f, c3 = 0.f;
#pragma unroll 4
  for (int r = 0; r < 16; ++r) {
    const int row = r0 + r;
    const float* base = (row < BS) ? (src + (size_t)row * DIM)
                                   : (tgt + (size_t)(row - BS) * DIM);
    float4 v = *reinterpret_cast<const float4*>(base + t * 4);
    *reinterpret_cast<int*>(dstbase + r * 16) = quant4(v);   // r15 = r
    c0 += v.x; c1 += v.y; c2 += v.z; c3 += v.w;
    float s = v.x*v.x + v.y*v.y + v.z*v.z + v.w*v.w;
#pragma unroll
    for (int off = 32; off > 0; off >>= 1) s += __shfl_down(s, off, 64);
    if (lane == 0) rs[r][wave] = s;
  }
  float4 cp = {c0, c1, c2, c3};
  *reinterpret_cast<float4*>(colpart + (size_t)R * 1024 + t * 4) = cp;
  __syncthreads();
  if (t < 16) sq[r0 + t] = (rs[t][0] + rs[t][1]) + (rs[t][2] + rs[t][3]);
}

// ---- kernel B: reduce 512 col-partial groups -> 8 ----
__global__ __launch_bounds__(1024) void colred_kernel(const float* __restrict__ colpart,
                                                      float* __restrict__ colp2) {
  const int b = blockIdx.x, t = threadIdx.x;   // 8 blocks x 1024 cols
  float s = 0.f;
  for (int g = b * 64; g < b * 64 + 64; ++g) s += colpart[(size_t)g * 1024 + t];
  colp2[b * 1024 + t] = s;
}

// ---- kernel C: bandwidth from analytic sum(L2) ----
__global__ __launch_bounds__(1024) void bw_kernel(const float* __restrict__ sq,
                                                  const float* __restrict__ colp2,
                                                  float* __restrict__ bwp) {
  const int t = threadIdx.x;
  double s1 = 0.0;
#pragma unroll
  for (int i = 0; i < 8; ++i) s1 += (double)sq[t + i * 1024];
  float s = 0.f;
#pragma unroll
  for (int j = 0; j < 8; ++j) s += colp2[j * 1024 + t];
  double s2 = (double)s * (double)s;
  __shared__ double r1[1024], r2[1024];
  r1[t] = s1; r2[t] = s2;
  __syncthreads();
  for (int off = 512; off > 0; off >>= 1) {
    if (t < off) { r1[t] += r1[t + off]; r2[t] += r2[t + off]; }
    __syncthreads();
  }
  if (t == 0) {
    const double n = (double)NTOT;
    double sumL2 = 2.0 * n * r1[0] - 2.0 * r2[0];
    double bw = sumL2 / (n * n - n);
    bw = bw / 4.0;  // KERNEL_MUL^(KERNEL_NUM//2) = 2^2
    const double LOG2E = 1.4426950408889634;
    for (int k = 0; k < 5; ++k)
      bwp[k] = (float)(-LOG2E / (bw * (double)(1 << k)));  // exp2-folded
  }
}

// stage one K=64 tile pair (A,B): 8KB each = 512 linear 16B chunks, 4/thread.
// Source is the tiled tb (already in LDS order) -> pure linear copy.
#define STAGE(kt1024, ldsA, ldsB)                                             \
  do {                                                                        \
    load_lds16(T + a0g + (kt1024), (ldsA) + (size_t)(wave * 64) * 16);        \
    load_lds16(T + a1g + (kt1024), (ldsA) + (size_t)(256 + wave * 64) * 16);  \
    load_lds16(T + b0g + (kt1024), (ldsB) + (size_t)(wave * 64) * 16);        \
    load_lds16(T + b1g + (kt1024), (ldsB) + (size_t)(256 + wave * 64) * 16);  \
  } while (0)

// one K=64 step: 2 k-halves x (4 ds_read_b128 + 4 MFMA 32x32x32_i8).
// Wave computes 64x64 as 2x2 of 32x32 tiles.
#define COMPUTE64(Abuf, Bbuf)                                                 \
  do {                                                                        \
    _Pragma("unroll")                                                         \
    for (int kk = 0; kk < 2; ++kk) {                                          \
      i32x4 fa0 = *reinterpret_cast<const i32x4*>(&(Abuf)[abase + kk * 512]); \
      i32x4 fa1 = *reinterpret_cast<const i32x4*>(&(Abuf)[abase + 2048 + kk * 512]); \
      i32x4 fb0 = *reinterpret_cast<const i32x4*>(&(Bbuf)[bbase + kk * 512]); \
      i32x4 fb1 = *reinterpret_cast<const i32x4*>(&(Bbuf)[bbase + 2048 + kk * 512]); \
      acc00 = __builtin_amdgcn_mfma_i32_32x32x32_i8(fa0, fb0, acc00, 0, 0, 0); \
      acc01 = __builtin_amdgcn_mfma_i32_32x32x32_i8(fa0, fb1, acc01, 0, 0, 0); \
      acc10 = __builtin_amdgcn_mfma_i32_32x32x32_i8(fa1, fb0, acc10, 0, 0, 0); \
      acc11 = __builtin_amdgcn_mfma_i32_32x32x32_i8(fa1, fb1, acc11, 0, 0, 0); \
    }                                                                         \
  } while (0)

#define BARR __builtin_amdgcn_s_barrier()

#define EXP5(x16) ({ float u_ = fast_exp2(x16);                               \
                     float u2_ = u_ * u_, u4_ = u2_ * u2_;                    \
                     float u8_ = u4_ * u4_, u16_ = u8_ * u8_;                 \
                     ((u_ + u2_) + (u4_ + u8_)) + u16_; })

// ---- kernel D: fused i8 Gram GEMM + RBF epilogue, upper-triangular tiles ----
// 128x128 tile, BK=64 i8, 4 waves (2x2, each 64x64 out), R13 skeleton:
// 32KB LDS -> 4 blocks/CU TLP + counted-vmcnt dbuf (never drain-0 in loop).
// i8 32x32x32 MFMA = 2x fp8 rate; integer accumulation exact.
__global__ __launch_bounds__(256, 4) void mmd_gemm(const unsigned char* __restrict__ T,
                                                   const float* __restrict__ sq,
                                                   const float* __restrict__ bwp,
                                                   float* __restrict__ partials) {
  __shared__ __align__(16) unsigned char sA0[8192], sA1[8192];
  __shared__ __align__(16) unsigned char sB0[8192], sB1[8192];
  __shared__ float wred[4];

  const int tid  = threadIdx.x;
  const int lane = tid & 63;
  const int wave = tid >> 6;       // 0..3
  const int wr   = wave >> 1;      // wave row (0..1)
  const int wc   = wave & 1;       // wave col (0..1)

  // XCD-aware chunked swizzle: 8 XCDs x 260 contiguous triangular tiles
  const int tno = (blockIdx.x & 7) * 260 + (blockIdx.x >> 3);
  // triangular decode: tile tno -> (bi, bj) with bi<=bj, f(bi)=bi*(129-bi)/2
  int bi = (int)((129.0f - fast_sqrt(129.0f * 129.0f - 8.0f * (float)tno)) * 0.5f);
  while (bi > 0 && bi * (129 - bi) / 2 > tno) --bi;
  while ((bi + 1) * (129 - (bi + 1)) / 2 <= tno) ++bi;
  const int bj = bi + (tno - bi * (129 - bi) / 2);

  // row-block bases (8 x 16-row blocks per 128-row tile)
  const int aRB = bi * 8, bRB = bj * 8;

  // staging source offsets: chunk f -> row-block f>>6, 16B chunk f&63
  const int f0 = tid, f1 = 256 + tid;
  const size_t a0g = (size_t)(aRB + (f0 >> 6)) * 16384 + (f0 & 63) * 16;
  const size_t a1g = (size_t)(aRB + (f1 >> 6)) * 16384 + (f1 & 63) * 16;
  const size_t b0g = (size_t)(bRB + (f0 >> 6)) * 16384 + (f0 & 63) * 16;
  const size_t b1g = (size_t)(bRB + (f1 >> 6)) * 16384 + (f1 & 63) * 16;

  i32x16 acc00 = {}, acc01 = {}, acc10 = {}, acc11 = {};

  const int col5 = lane & 31;      // m (A) / n (B) within a 32-tile
  const int hi32 = lane >> 5;      // 16-k subgroup
  // frag byte offset: row = w*64 + tm*32 + col5, group g = kk*2 + hi32:
  //   (row>>4)*1024 + g*256 + (row&15)*16; tm adds 2048, kk adds 512
  const int abase = (wr * 4 + (col5 >> 4)) * 1024 + hi32 * 256 + (lane & 15) * 16;
  const int bbase = (wc * 4 + (col5 >> 4)) * 1024 + hi32 * 256 + (lane & 15) * 16;

  // prologue: stage K-tile 0 into buf0 (4 loads in flight)
  STAGE(0, sA0, sB0);

  for (int t = 0; t < 8; ++t) {
    // even tile 2t in buf0; stage odd tile 2t+1 into buf1
    STAGE((2 * t + 1) * 1024, sA1, sB1);
    asm volatile("s_waitcnt vmcnt(4)" ::: "memory");   // tile-2t loads landed
    BARR;
    __builtin_amdgcn_sched_barrier(0);
    COMPUTE64(sA0, sB0);
    __builtin_amdgcn_sched_barrier(0);
    BARR;                                              // buf0 reads done everywhere

    // odd tile 2t+1 in buf1; stage even tile 2t+2 into buf0
    if (t < 7) {
      STAGE((2 * t + 2) * 1024, sA0, sB0);
      asm volatile("s_waitcnt vmcnt(4)" ::: "memory");
    } else {
      asm volatile("s_waitcnt vmcnt(0)" ::: "memory");
    }
    BARR;
    __builtin_amdgcn_sched_barrier(0);
    COMPUTE64(sA1, sB1);
    __builtin_amdgcn_sched_barrier(0);
    BARR;                                              // buf1 reads done everywhere
  }

  // epilogue: G = acc/QS^2 (exact int); x = l2*ni0 in exp2 domain; u=2^(x/16)
  // C/D layout (verified): col = lane&31, row = (r&3) + 8*(r>>2) + 4*(lane>>5)
  const float s16 = bwp[0] * 0.0625f;          // -log2e/(16*bw)
  const float c2i = -2.f * s16 / (QS * QS);

  const float bj0 = sq[bj * 128 + wc * 64 + col5] * s16;        // tn=0
  const float bj1 = sq[bj * 128 + wc * 64 + 32 + col5] * s16;   // tn=1

  float tsum = 0.f;
#pragma unroll
  for (int tm = 0; tm < 2; ++tm) {
    const int rbaseq = bi * 128 + wr * 64 + tm * 32 + 4 * hi32;
#pragma unroll
    for (int q = 0; q < 4; ++q) {
#pragma unroll
      for (int p = 0; p < 4; ++p) {
        const float ai = sq[rbaseq + q * 8 + p] * s16;
        const int r = q * 4 + p;
        const int v0 = tm ? acc10[r] : acc00[r];
        const int v1 = tm ? acc11[r] : acc01[r];
        tsum += EXP5(fmaf((float)v0, c2i, ai + bj0));
        tsum += EXP5(fmaf((float)v1, c2i, ai + bj1));
      }
    }
  }

#pragma unroll
  for (int off = 32; off > 0; off >>= 1) tsum += __shfl_down(tsum, off, 64);
  if (lane == 0) wred[wave] = tsum;
  __syncthreads();
  if (tid == 0) {
    float sign = ((bi < 32) == (bj < 32)) ? 1.f : -1.f;
    float wgt  = (bi == bj) ? 1.f : 2.f;
    partials[tno] = sign * wgt * ((wred[0] + wred[1]) + (wred[2] + wred[3]));
  }
}

// ---- kernel E: final reduction ----
__global__ __launch_bounds__(256) void finish_kernel(const float* __restrict__ partials,
                                                     float* __restrict__ out) {
  const int t = threadIdx.x;
  double s = 0.0;
  for (int i = t; i < NTRI; i += 256) s += (double)partials[i];
  __shared__ double rd[256];
  rd[t] = s;
  __syncthreads();
  for (int off = 128; off > 0; off >>= 1) {
    if (t < off) rd[t] += rd[t + off];
    __syncthreads();
  }
  if (t == 0) out[0] = (float)(rd[0] / 16777216.0);  // / bs^2
}

extern "C" void kernel_launch(void* const* d_in, const int* in_sizes, int n_in,
                              void* d_out, int out_size, void* d_ws, size_t ws_size,
                              hipStream_t stream) {
  const float* src = (const float*)d_in[0];
  const float* tgt = (const float*)d_in[1];
  char* ws = (char*)d_ws;
  unsigned char* tb = (unsigned char*)(ws + OFF_TB);
  float* sq       = (float*)(ws + OFF_SQ);
  float* colpart  = (float*)(ws + OFF_COLPART);
  float* colp2    = (float*)(ws + OFF_COLP2);
  float* bwp      = (float*)(ws + OFF_BWP);
  float* partials = (float*)(ws + OFF_PART);

  prep_kernel<<<dim3(512), dim3(256), 0, stream>>>(src, tgt, tb, sq, colpart);
  colred_kernel<<<dim3(8), dim3(1024), 0, stream>>>(colpart, colp2);
  bw_kernel<<<dim3(1), dim3(1024), 0, stream>>>(sq, colp2, bwp);
  mmd_gemm<<<dim3(NTRI), dim3(256), 0, stream>>>(tb, sq, bwp, partials);
  finish_kernel<<<dim3(1), dim3(256), 0, stream>>>(partials, (float*)d_out);
}